// Round 12
// baseline (120.994 us; speedup 1.0000x reference)
//
#include <hip/hip_runtime.h>
#include <hip/hip_bf16.h>
#include <cstdint>
#include <cstddef>

// Problem constants
#define B_    16
#define CIN   960
#define HH    56
#define WW_   56
#define GG    2
#define COUT  96
#define NK_   5
#define PIX   3136   // 56*56
#define NCH   30     // K-chunks of 32

// Workspace layout (float indices):
//   wf  bf16 fragment-ordered, PADDED: [NCH][8192 B] (frags in first 6144 B)
//   bias f32[96] at 61440 ; y bf16[16][96][3136] at 61568
#define WF_OFF   0
#define BIAS_OFF 61440
#define Y_OFF    61568

typedef __attribute__((ext_vector_type(8))) short bf16x8;
typedef __attribute__((ext_vector_type(4))) float f32x4;

__device__ __forceinline__ short f2b(float f) {
    union { float f; unsigned u; } c; c.f = f;
    unsigned r = (c.u + 0x7FFFu + ((c.u >> 16) & 1u)) >> 16;
    return (short)r;
}
__device__ __forceinline__ float b2f(short s) {
    union { unsigned u; float f; } c;
    c.u = ((unsigned)(unsigned short)s) << 16;
    return c.f;
}

// ---------------------------------------------------------------------------
// K0a: fragment-ordered weights, padded per chunk (identical to 93.5 build).
__global__ void prep_wb(const float* __restrict__ pw, const float* __restrict__ sc,
                        short* __restrict__ wf) {
    int idx = blockIdx.x * 256 + threadIdx.x;   // (n*6+f)*64 + lane
    if (idx >= NCH * 6 * 64) return;
    const int lane = idx & 63;
    const int nf   = idx >> 6;
    const int f    = nf % 6;
    const int n    = nf / 6;
    const int o    = f * 16 + (lane & 15);
    const int c0   = n * 32 + (lane >> 4) * 8;
    bf16x8 v;
#pragma unroll
    for (int k = 0; k < 8; ++k)
        v[k] = f2b(pw[o * CIN + c0 + k] * (sc[c0 + k] + 1e-5f));
    *(bf16x8*)((char*)wf + (size_t)n * 8192 + (f * 64 + lane) * 16) = v;
}

// bias_o[o] = sum_c proj_w[o][c] * local_bias[c]   (96 blocks x 1 wave)
__global__ void prep_bias(const float* __restrict__ pw, const float* __restrict__ bi,
                          float* __restrict__ bias) {
    const int o = blockIdx.x;
    const int l = threadIdx.x;
    float s = 0.f;
    for (int c = l; c < CIN; c += 64) s += pw[o * CIN + c] * bi[c];
#pragma unroll
    for (int off = 32; off; off >>= 1) s += __shfl_down(s, off);
    if (l == 0) bias[o] = s;
}

// ---------------------------------------------------------------------------
// K1: y[b,o,px] = sum_c W[o][c]*x[b,c,px]   (bias in finalize; y bf16)
// ZERO-LDS / ZERO-BARRIER register GEMM. 512 thr / 8 waves (2M x 4N); wave
// (m,n) owns o in [m*48,m*48+48) x 16 px. Per chunk per wave: 8 coalesced
// global_load_dword build the B-frag in regs (lane l -> x[ch0+(l>>4)*8+k]
// [px0+n*16+(l&15)]; 16 lanes = one 64B line), 3 global_load_dwordx4 read
// the fragment-ordered W (L2-hot), 8 f2b, 3 MFMA. Static A/B double buffer,
// distance-1 prefetch; latency hidden by TLP (no lockstep, no LDS).
__global__ __launch_bounds__(512)
void conv_mfma(const float* __restrict__ x, const short* __restrict__ wf,
               short* __restrict__ yb) {
    const int tid  = threadIdx.x;
    const int lane = tid & 63;
    const int wv   = tid >> 6;          // 0..7
    const int m    = wv >> 2;           // o-half
    const int n    = wv & 3;            // px tile
    const int b    = blockIdx.y;
    const int px0  = blockIdx.x * 64;

    // B-frag source: lane's pixel column, channel row ch0+(lane>>4)*8+k
    const float* xpx = x + (size_t)b * CIN * PIX + px0 + n * 16 + (lane & 15);
    const int kb8 = (lane >> 4) * 8;
    // A-frag source: fragment-ordered W, wave m reads frags 3m..3m+2
    const char* wfl = (const char*)wf + m * 3072 + lane * 16;

    f32x4 acc0 = {0.f, 0.f, 0.f, 0.f};
    f32x4 acc1 = {0.f, 0.f, 0.f, 0.f};
    f32x4 acc2 = {0.f, 0.f, 0.f, 0.f};

    float  xA[8], xB[8];
    bf16x8 wA0, wA1, wA2, wB0, wB1, wB2;

#define LOADX(DST, N)                                                            \
    {                                                                            \
        _Pragma("unroll")                                                        \
        for (int k = 0; k < 8; ++k)                                              \
            DST[k] = xpx[(size_t)((N) * 32 + kb8 + k) * PIX];                    \
    }
#define LOADW(D0, D1, D2, N)                                                     \
    {                                                                            \
        const char* wp_ = wfl + (size_t)(N) * 8192;                              \
        D0 = *(const bf16x8*)(wp_);                                              \
        D1 = *(const bf16x8*)(wp_ + 1024);                                       \
        D2 = *(const bf16x8*)(wp_ + 2048);                                       \
    }
#define COMP(XV, W0, W1, W2)                                                     \
    {                                                                            \
        bf16x8 bf;                                                               \
        _Pragma("unroll")                                                        \
        for (int k = 0; k < 8; ++k) bf[k] = f2b(XV[k]);                          \
        acc0 = __builtin_amdgcn_mfma_f32_16x16x32_bf16(W0, bf, acc0, 0, 0, 0);   \
        acc1 = __builtin_amdgcn_mfma_f32_16x16x32_bf16(W1, bf, acc1, 0, 0, 0);   \
        acc2 = __builtin_amdgcn_mfma_f32_16x16x32_bf16(W2, bf, acc2, 0, 0, 0);   \
    }

    // prologue: chunk 0 -> A
    LOADX(xA, 0);
    LOADW(wA0, wA1, wA2, 0);

#pragma unroll 1
    for (int p = 0; p < 14; ++p) {
        LOADX(xB, 2 * p + 1);
        LOADW(wB0, wB1, wB2, 2 * p + 1);
        COMP(xA, wA0, wA1, wA2);            // chunk 2p
        LOADX(xA, 2 * p + 2);
        LOADW(wA0, wA1, wA2, 2 * p + 2);
        COMP(xB, wB0, wB1, wB2);            // chunk 2p+1
    }
    // tail: A holds chunk 28
    LOADX(xB, 29);
    LOADW(wB0, wB1, wB2, 29);
    COMP(xA, wA0, wA1, wA2);                // chunk 28
    COMP(xB, wB0, wB1, wB2);                // chunk 29
#undef COMP
#undef LOADW
#undef LOADX

    // epilogue: C/D col(px) = lane&15, row(o) = (lane>>4)*4 + r
    short* yp = yb + (size_t)b * COUT * PIX + px0 + n * 16 + (lane & 15);
    const int o0 = m * 48 + (lane >> 4) * 4;
#pragma unroll
    for (int r = 0; r < 4; ++r) yp[(size_t)(o0 +      r) * PIX] = f2b(acc0[r]);
#pragma unroll
    for (int r = 0; r < 4; ++r) yp[(size_t)(o0 + 16 + r) * PIX] = f2b(acc1[r]);
#pragma unroll
    for (int r = 0; r < 4; ++r) yp[(size_t)(o0 + 32 + r) * PIX] = f2b(acc2[r]);
}

// ---------------------------------------------------------------------------
// Antialiased 58->56 triangle weights; tap indices mapped to the 56-grid.
__device__ __forceinline__ void rweights56(int o, short* idx, float* wt) {
    const float ratio = 58.0f / 56.0f;
    const float kinv  = 56.0f / 58.0f;
    const float sf = ((float)o + 0.5f) * ratio - 0.5f;
    const int f0 = (int)floorf(sf);
    float sum = 0.f;
#pragma unroll
    for (int t = 0; t < 4; ++t) {
        int i = f0 - 1 + t;
        float w = fmaxf(1.0f - fabsf(sf - (float)i) * kinv, 0.0f);
        if (i < 0 || i > 57) w = 0.0f;
        idx[t] = (short)min(HH - 1, max(0, i - 1));
        wt[t] = w;
        sum += w;
    }
    const float inv = 1.0f / sum;
#pragma unroll
    for (int t = 0; t < 4; ++t) wt[t] *= inv;
}

// ---------------------------------------------------------------------------
// K2: EXACT round-8 finalize (1 px/thread; proven fastest).
__global__ __launch_bounds__(256)
void finalize(const float* __restrict__ x, const int* __restrict__ pad_hv,
              const int* __restrict__ idt, const short* __restrict__ yb,
              const float* __restrict__ bias, const float* __restrict__ alpha_p,
              float* __restrict__ out) {
    const int bc = blockIdx.x;          // b*96 + co
    const int co = bc % COUT;
    const int b  = bc / COUT;
    const int t  = threadIdx.x;

    __shared__ float  ylds[PIX];
    __shared__ float4 wt4[56];
    __shared__ short4 id4[56];
    __shared__ int   ish[10], isv[10], ipl[10];
    __shared__ float fid[10];

    if (t < 10) {
        const int g = t / 5;
        const int k = t - g * 5;
        const int slot = co * NK_ + k;
        ish[t] = pad_hv[slot * 4 + g];
        isv[t] = pad_hv[slot * 4 + 2 + g];
        fid[t] = (idt[slot * 2 + g] >= 0) ? 1.f : 0.f;
        ipl[t] = (g * (COUT * NK_) + slot) * PIX;
    }
    if (t < 56) {
        short ii[4]; float ww[4];
        rweights56(t, ii, ww);
        wt4[t] = make_float4(ww[0], ww[1], ww[2], ww[3]);
        id4[t] = make_short4(ii[0], ii[1], ii[2], ii[3]);
    }
    {
        const short* yp = yb + (size_t)bc * PIX;
#pragma unroll 1
        for (int i = t; i < PIX / 4; i += 256) {
            const short4 s4 = *(const short4*)(yp + i * 4);
            *(float4*)(ylds + i * 4) =
                make_float4(b2f(s4.x), b2f(s4.y), b2f(s4.z), b2f(s4.w));
        }
    }
    __syncthreads();

    int   ish_r[10], isv_r[10], ipl_r[10];
    float fid_r[10];
#pragma unroll
    for (int p = 0; p < 10; ++p) {
        ish_r[p] = ish[p]; isv_r[p] = isv[p];
        ipl_r[p] = ipl[p]; fid_r[p] = fid[p];
    }

    const float alpha = alpha_p[0];
    const float ia    = 1.0f - alpha;
    const float bco   = bias[co];
    const float* xb = x + (size_t)b * CIN * PIX;
    float* op = out + (size_t)bc * PIX;

#pragma unroll 1
    for (int px = t; px < PIX; px += 256) {
        const int h = (px * 18725) >> 20;
        const int w = px - h * WW_;
        const int hrow = px - w;

        float accg = 0.f;
#pragma unroll
        for (int p = 0; p < 10; ++p) {
            const float* xc = xb + ipl_r[p];
            const int jw = w + ish_r[p];
            const float mh = (jw >= -1 && jw <= WW_) ? 1.f : 0.f;
            accg += mh * xc[hrow + min(WW_ - 1, max(0, jw))];

            const int iv = h + isv_r[p];
            const float mv = (iv >= -1 && iv <= HH) ? 1.f : 0.f;
            accg += mv * xc[min(HH - 1, max(0, iv)) * WW_ + w];

            accg += fid_r[p] * xc[px];
        }

        const float4 ww4 = wt4[w];
        const short4 iw4 = id4[w];
        const float4 wh4 = wt4[h];
        const short4 ih4 = id4[h];
        float accl = 0.f;
#pragma unroll
        for (int a = 0; a < 4; ++a) {
            const int row = ((const short*)&ih4)[a] * WW_;
            const float* yr = ylds + row;
            float rs;
            rs = ww4.x * yr[iw4.x];
            rs = fmaf(ww4.y, yr[iw4.y], rs);
            rs = fmaf(ww4.z, yr[iw4.z], rs);
            rs = fmaf(ww4.w, yr[iw4.w], rs);
            accl = fmaf(((const float*)&wh4)[a], rs, accl);
        }
        accl += bco;

        op[px] = alpha * accg * (1.0f / 3.0f) + ia * accl;
    }
}

// ---------------------------------------------------------------------------
extern "C" void kernel_launch(void* const* d_in, const int* in_sizes, int n_in,
                              void* d_out, int out_size, void* d_ws, size_t ws_size,
                              hipStream_t stream) {
    const float* x      = (const float*)d_in[0];
    const int*   pad_hv = (const int*)d_in[1];
    const int*   idt    = (const int*)d_in[2];
    const float* lsc    = (const float*)d_in[3];
    const float* lbi    = (const float*)d_in[4];
    const float* pw     = (const float*)d_in[5];
    const float* alpha  = (const float*)d_in[6];
    float* out = (float*)d_out;

    float* ws   = (float*)d_ws;
    short* wf   = (short*)(ws + WF_OFF);
    float* bias = ws + BIAS_OFF;
    short* yb   = (short*)(ws + Y_OFF);

    prep_wb<<<(NCH * 6 * 64 + 255) / 256, 256, 0, stream>>>(pw, lsc, wf);
    prep_bias<<<COUT, 64, 0, stream>>>(pw, lbi, bias);
    conv_mfma<<<dim3(PIX / 64, B_), 512, 0, stream>>>(x, wf, yb);
    finalize<<<B_ * COUT, 256, 0, stream>>>(x, pad_hv, idt, yb, bias, alpha, out);
}

// Round 13
// 101.757 us; speedup vs baseline: 1.1891x; 1.1891x over previous
//
#include <hip/hip_runtime.h>
#include <hip/hip_bf16.h>
#include <cstdint>
#include <cstddef>

// Problem constants
#define B_    16
#define CIN   960
#define HH    56
#define WW_   56
#define GG    2
#define COUT  96
#define NK_   5
#define PIX   3136   // 56*56
#define NCH   30     // K-chunks of 32

// Workspace layout (float indices):
//   wf  bf16 fragment-ordered, PADDED: [NCH][8192 B] (frags in first 6144 B)
//   bias f32[96] at 61440 ; y bf16[16][96][3136] at 61568
#define WF_OFF   0
#define BIAS_OFF 61440
#define Y_OFF    61568

typedef __attribute__((ext_vector_type(8))) short bf16x8;
typedef __attribute__((ext_vector_type(4))) float f32x4;

__device__ __forceinline__ short f2b(float f) {
    union { float f; unsigned u; } c; c.f = f;
    unsigned r = (c.u + 0x7FFFu + ((c.u >> 16) & 1u)) >> 16;
    return (short)r;
}
__device__ __forceinline__ float b2f(short s) {
    union { unsigned u; float f; } c;
    c.u = ((unsigned)(unsigned short)s) << 16;
    return c.f;
}

#define GLOAD_LDS16(gp, lp)                                                        \
    __builtin_amdgcn_global_load_lds(                                              \
        (const __attribute__((address_space(1))) unsigned*)(gp),                   \
        (__attribute__((address_space(3))) unsigned*)(lp), 16, 0, 0)

// ---------------------------------------------------------------------------
// K0a: fragment-ordered weights, padded per chunk (identical to 93.5 build).
__global__ void prep_wb(const float* __restrict__ pw, const float* __restrict__ sc,
                        short* __restrict__ wf) {
    int idx = blockIdx.x * 256 + threadIdx.x;   // (n*6+f)*64 + lane
    if (idx >= NCH * 6 * 64) return;
    const int lane = idx & 63;
    const int nf   = idx >> 6;
    const int f    = nf % 6;
    const int n    = nf / 6;
    const int o    = f * 16 + (lane & 15);
    const int c0   = n * 32 + (lane >> 4) * 8;
    bf16x8 v;
#pragma unroll
    for (int k = 0; k < 8; ++k)
        v[k] = f2b(pw[o * CIN + c0 + k] * (sc[c0 + k] + 1e-5f));
    *(bf16x8*)((char*)wf + (size_t)n * 8192 + (f * 64 + lane) * 16) = v;
}

// bias_o[o] = sum_c proj_w[o][c] * local_bias[c]   (96 blocks x 1 wave)
__global__ void prep_bias(const float* __restrict__ pw, const float* __restrict__ bi,
                          float* __restrict__ bias) {
    const int o = blockIdx.x;
    const int l = threadIdx.x;
    float s = 0.f;
    for (int c = l; c < CIN; c += 64) s += pw[o * CIN + c] * bi[c];
#pragma unroll
    for (int off = 32; off; off >>= 1) s += __shfl_down(s, off);
    if (l == 0) bias[o] = s;
}

// ---------------------------------------------------------------------------
// K1: y[b,o,px] = sum_c W[o][c]*x[b,c,px]   (bias in finalize; y bf16)
// 512 thr / 8 waves (2M x 4N), 64 px x 96 out per block.
// x path: per chunk per wave, 4 coalesced global_load_dword -> regs ->
//   4 f2b -> ONE ds_write_b64 into bf16 k-contiguous LDS [kb][px][8ch]
//   (write: 64-lane sequential; read: one ds_read_b128, 256B contiguous per
//   16-lane group -- both conflict-free). 3 reg buffers = distance-2 cover.
// W path: proven gload_lds DMA, 3 LDS buffers (DMA issued post-barrier can
//   never land on a buffer being read).
// vmcnt ledger: 5 issues/step (4 x + 1 W); steady pre-wait outstanding = 14
//   (chunk n:5, n+1:5, x(n+2):4) -> vmcnt(9) retires chunk n. Tail: 5 -> 0.
// LDS = 2*4KB (x) + 3*8KB (W) = 32KB -> up to 4 blocks/CU.
__global__ __launch_bounds__(512)
void conv_mfma(const float* __restrict__ x, const short* __restrict__ wf,
               short* __restrict__ yb) {
    const int tid  = threadIdx.x;
    const int lane = tid & 63;
    const int wv   = tid >> 6;          // 0..7
    const int m    = wv >> 2;           // o-half
    const int n    = wv & 3;            // px tile
    const int b    = blockIdx.y;
    const int px0  = blockIdx.x * 64;

    __shared__ __align__(16) char xls[2 * 4096];   // bf16 x [kb][64px][8ch]
    __shared__ __align__(16) char wls[3 * 8192];   // W chunks (r8 frag format)

    // staging role: wave wv stages slab kb = wv>>1, byte-half h = wv&1
    const int skb = wv >> 1;
    const int sh8 = (wv & 1) * 8;
    const float* xsrc = x + (size_t)b * CIN * PIX + px0 + lane
                        + (size_t)(skb * 8 + (wv & 1) * 4) * PIX;
    const int wxb = skb * 1024 + lane * 16 + sh8;        // x LDS write byte
    const char* wfB = (const char*)wf;
    const int wsub = wv * 1024 + lane * 16;              // W src per-lane byte

    // compute role
    const int bbyte = (lane >> 4) * 1024 + (n * 16 + (lane & 15)) * 16;
    const int abyte = m * 3072 + lane * 16;              // + f*1024 + WBI*8192

    f32x4 acc0 = {0.f, 0.f, 0.f, 0.f};
    f32x4 acc1 = {0.f, 0.f, 0.f, 0.f};
    f32x4 acc2 = {0.f, 0.f, 0.f, 0.f};

    float vX0[4], vX1[4], vX2[4];

#define XLOAD(D, N)                                                              \
    {                                                                            \
        _Pragma("unroll")                                                        \
        for (int k = 0; k < 4; ++k)                                              \
            D[k] = xsrc[(size_t)((N) * 32 + k) * PIX];                           \
    }
#define WDMA(N, DB)                                                              \
    GLOAD_LDS16(wfB + (size_t)(N) * 8192 + wsub, wls + (DB) * 8192 + wv * 1024);

// STEP: [issue x(n+2)] wait chunk n -> pack/write x(n) -> lgkm+barrier ->
//       [issue W(n+2) DMA] -> compute chunk n (1 B-read + 3 A-reads + 3 MFMA)
#define STEP(n_, XBI, WBI, WDN, RCUR, RNXT, VM, ISSUE)                           \
    {                                                                            \
        if (ISSUE) XLOAD(RNXT, (n_) + 2);                                        \
        asm volatile("s_waitcnt vmcnt(" #VM ")" ::: "memory");                   \
        {                                                                        \
            short4 pk;                                                           \
            pk.x = f2b(RCUR[0]); pk.y = f2b(RCUR[1]);                            \
            pk.z = f2b(RCUR[2]); pk.w = f2b(RCUR[3]);                            \
            *(short4*)(xls + (XBI) * 4096 + wxb) = pk;                           \
        }                                                                        \
        asm volatile("s_waitcnt lgkmcnt(0)" ::: "memory");                       \
        asm volatile("s_barrier" ::: "memory");                                  \
        if (ISSUE) WDMA((n_) + 2, WDN);                                          \
        {                                                                        \
            const bf16x8 bf = *(const bf16x8*)(xls + (XBI) * 4096 + bbyte);      \
            const char* wp_ = wls + (WBI) * 8192 + abyte;                        \
            const bf16x8 a0 = *(const bf16x8*)(wp_);                             \
            const bf16x8 a1 = *(const bf16x8*)(wp_ + 1024);                      \
            const bf16x8 a2 = *(const bf16x8*)(wp_ + 2048);                      \
            acc0 = __builtin_amdgcn_mfma_f32_16x16x32_bf16(a0, bf, acc0, 0,0,0); \
            acc1 = __builtin_amdgcn_mfma_f32_16x16x32_bf16(a1, bf, acc1, 0,0,0); \
            acc2 = __builtin_amdgcn_mfma_f32_16x16x32_bf16(a2, bf, acc2, 0,0,0); \
        }                                                                        \
    }

    // prologue: chunks 0,1 in flight (x->regs, W->LDS buf 0,1)
    XLOAD(vX0, 0);
    WDMA(0, 0);
    XLOAD(vX1, 1);
    WDMA(1, 1);

#pragma unroll 1
    for (int mm = 0; mm < 4; ++mm) {
        const int n0 = mm * 6;
        STEP(n0 + 0, 0, 0, 2, vX0, vX2, 9, 1);
        STEP(n0 + 1, 1, 1, 0, vX1, vX0, 9, 1);
        STEP(n0 + 2, 0, 2, 1, vX2, vX1, 9, 1);
        STEP(n0 + 3, 1, 0, 2, vX0, vX2, 9, 1);
        STEP(n0 + 4, 0, 1, 0, vX1, vX0, 9, 1);
        STEP(n0 + 5, 1, 2, 1, vX2, vX1, 9, 1);
    }
    STEP(24, 0, 0, 2, vX0, vX2, 9, 1);
    STEP(25, 1, 1, 0, vX1, vX0, 9, 1);
    STEP(26, 0, 2, 1, vX2, vX1, 9, 1);
    STEP(27, 1, 0, 2, vX0, vX2, 9, 1);
    STEP(28, 0, 1, 0, vX1, vX1, 5, 0);
    STEP(29, 1, 2, 1, vX2, vX2, 0, 0);
#undef STEP
#undef WDMA
#undef XLOAD

    // epilogue: C/D col(px) = lane&15, row(o) = (lane>>4)*4 + r
    short* yp = yb + (size_t)b * COUT * PIX + px0 + n * 16 + (lane & 15);
    const int o0 = m * 48 + (lane >> 4) * 4;
#pragma unroll
    for (int r = 0; r < 4; ++r) yp[(size_t)(o0 +      r) * PIX] = f2b(acc0[r]);
#pragma unroll
    for (int r = 0; r < 4; ++r) yp[(size_t)(o0 + 16 + r) * PIX] = f2b(acc1[r]);
#pragma unroll
    for (int r = 0; r < 4; ++r) yp[(size_t)(o0 + 32 + r) * PIX] = f2b(acc2[r]);
}

// ---------------------------------------------------------------------------
// Antialiased 58->56 triangle weights; tap indices mapped to the 56-grid.
__device__ __forceinline__ void rweights56(int o, short* idx, float* wt) {
    const float ratio = 58.0f / 56.0f;
    const float kinv  = 56.0f / 58.0f;
    const float sf = ((float)o + 0.5f) * ratio - 0.5f;
    const int f0 = (int)floorf(sf);
    float sum = 0.f;
#pragma unroll
    for (int t = 0; t < 4; ++t) {
        int i = f0 - 1 + t;
        float w = fmaxf(1.0f - fabsf(sf - (float)i) * kinv, 0.0f);
        if (i < 0 || i > 57) w = 0.0f;
        idx[t] = (short)min(HH - 1, max(0, i - 1));
        wt[t] = w;
        sum += w;
    }
    const float inv = 1.0f / sum;
#pragma unroll
    for (int t = 0; t < 4; ++t) wt[t] *= inv;
}

// ---------------------------------------------------------------------------
// K2: EXACT round-8 finalize (1 px/thread; proven fastest).
__global__ __launch_bounds__(256)
void finalize(const float* __restrict__ x, const int* __restrict__ pad_hv,
              const int* __restrict__ idt, const short* __restrict__ yb,
              const float* __restrict__ bias, const float* __restrict__ alpha_p,
              float* __restrict__ out) {
    const int bc = blockIdx.x;          // b*96 + co
    const int co = bc % COUT;
    const int b  = bc / COUT;
    const int t  = threadIdx.x;

    __shared__ float  ylds[PIX];
    __shared__ float4 wt4[56];
    __shared__ short4 id4[56];
    __shared__ int   ish[10], isv[10], ipl[10];
    __shared__ float fid[10];

    if (t < 10) {
        const int g = t / 5;
        const int k = t - g * 5;
        const int slot = co * NK_ + k;
        ish[t] = pad_hv[slot * 4 + g];
        isv[t] = pad_hv[slot * 4 + 2 + g];
        fid[t] = (idt[slot * 2 + g] >= 0) ? 1.f : 0.f;
        ipl[t] = (g * (COUT * NK_) + slot) * PIX;
    }
    if (t < 56) {
        short ii[4]; float ww[4];
        rweights56(t, ii, ww);
        wt4[t] = make_float4(ww[0], ww[1], ww[2], ww[3]);
        id4[t] = make_short4(ii[0], ii[1], ii[2], ii[3]);
    }
    {
        const short* yp = yb + (size_t)bc * PIX;
#pragma unroll 1
        for (int i = t; i < PIX / 4; i += 256) {
            const short4 s4 = *(const short4*)(yp + i * 4);
            *(float4*)(ylds + i * 4) =
                make_float4(b2f(s4.x), b2f(s4.y), b2f(s4.z), b2f(s4.w));
        }
    }
    __syncthreads();

    int   ish_r[10], isv_r[10], ipl_r[10];
    float fid_r[10];
#pragma unroll
    for (int p = 0; p < 10; ++p) {
        ish_r[p] = ish[p]; isv_r[p] = isv[p];
        ipl_r[p] = ipl[p]; fid_r[p] = fid[p];
    }

    const float alpha = alpha_p[0];
    const float ia    = 1.0f - alpha;
    const float bco   = bias[co];
    const float* xb = x + (size_t)b * CIN * PIX;
    float* op = out + (size_t)bc * PIX;

#pragma unroll 1
    for (int px = t; px < PIX; px += 256) {
        const int h = (px * 18725) >> 20;
        const int w = px - h * WW_;
        const int hrow = px - w;

        float accg = 0.f;
#pragma unroll
        for (int p = 0; p < 10; ++p) {
            const float* xc = xb + ipl_r[p];
            const int jw = w + ish_r[p];
            const float mh = (jw >= -1 && jw <= WW_) ? 1.f : 0.f;
            accg += mh * xc[hrow + min(WW_ - 1, max(0, jw))];

            const int iv = h + isv_r[p];
            const float mv = (iv >= -1 && iv <= HH) ? 1.f : 0.f;
            accg += mv * xc[min(HH - 1, max(0, iv)) * WW_ + w];

            accg += fid_r[p] * xc[px];
        }

        const float4 ww4 = wt4[w];
        const short4 iw4 = id4[w];
        const float4 wh4 = wt4[h];
        const short4 ih4 = id4[h];
        float accl = 0.f;
#pragma unroll
        for (int a = 0; a < 4; ++a) {
            const int row = ((const short*)&ih4)[a] * WW_;
            const float* yr = ylds + row;
            float rs;
            rs = ww4.x * yr[iw4.x];
            rs = fmaf(ww4.y, yr[iw4.y], rs);
            rs = fmaf(ww4.z, yr[iw4.z], rs);
            rs = fmaf(ww4.w, yr[iw4.w], rs);
            accl = fmaf(((const float*)&wh4)[a], rs, accl);
        }
        accl += bco;

        op[px] = alpha * accg * (1.0f / 3.0f) + ia * accl;
    }
}

// ---------------------------------------------------------------------------
extern "C" void kernel_launch(void* const* d_in, const int* in_sizes, int n_in,
                              void* d_out, int out_size, void* d_ws, size_t ws_size,
                              hipStream_t stream) {
    const float* x      = (const float*)d_in[0];
    const int*   pad_hv = (const int*)d_in[1];
    const int*   idt    = (const int*)d_in[2];
    const float* lsc    = (const float*)d_in[3];
    const float* lbi    = (const float*)d_in[4];
    const float* pw     = (const float*)d_in[5];
    const float* alpha  = (const float*)d_in[6];
    float* out = (float*)d_out;

    float* ws   = (float*)d_ws;
    short* wf   = (short*)(ws + WF_OFF);
    float* bias = ws + BIAS_OFF;
    short* yb   = (short*)(ws + Y_OFF);

    prep_wb<<<(NCH * 6 * 64 + 255) / 256, 256, 0, stream>>>(pw, lsc, wf);
    prep_bias<<<COUT, 64, 0, stream>>>(pw, lbi, bias);
    conv_mfma<<<dim3(PIX / 64, B_), 512, 0, stream>>>(x, wf, yb);
    finalize<<<B_ * COUT, 256, 0, stream>>>(x, pad_hv, idt, yb, bias, alpha, out);
}

// Round 14
// 96.888 us; speedup vs baseline: 1.2488x; 1.0503x over previous
//
#include <hip/hip_runtime.h>
#include <hip/hip_bf16.h>
#include <cstdint>
#include <cstddef>

// Problem constants
#define B_    16
#define CIN   960
#define HH    56
#define WW_   56
#define GG    2
#define COUT  96
#define NK_   5
#define PIX   3136   // 56*56
#define NCH   30     // K-chunks of 32

// Workspace layout (float indices):
//   wf  bf16 fragment-ordered, PADDED: [NCH][8192 B] (frags in first 6144 B)
//   bias f32[96] at 61440 ; y bf16[16][96][3136] at 61568
#define WF_OFF   0
#define BIAS_OFF 61440
#define Y_OFF    61568

typedef __attribute__((ext_vector_type(8))) short bf16x8;
typedef __attribute__((ext_vector_type(4))) float f32x4;

__device__ __forceinline__ short f2b(float f) {
    union { float f; unsigned u; } c; c.f = f;
    unsigned r = (c.u + 0x7FFFu + ((c.u >> 16) & 1u)) >> 16;
    return (short)r;
}
__device__ __forceinline__ float b2f(short s) {
    union { unsigned u; float f; } c;
    c.u = ((unsigned)(unsigned short)s) << 16;
    return c.f;
}

#define GLOAD_LDS16(gp, lp)                                                        \
    __builtin_amdgcn_global_load_lds(                                              \
        (const __attribute__((address_space(1))) unsigned*)(gp),                   \
        (__attribute__((address_space(3))) unsigned*)(lp), 16, 0, 0)

// ---------------------------------------------------------------------------
// K0a: fragment-ordered weights, padded per chunk (identical to 93.5 build).
__global__ void prep_wb(const float* __restrict__ pw, const float* __restrict__ sc,
                        short* __restrict__ wf) {
    int idx = blockIdx.x * 256 + threadIdx.x;   // (n*6+f)*64 + lane
    if (idx >= NCH * 6 * 64) return;
    const int lane = idx & 63;
    const int nf   = idx >> 6;
    const int f    = nf % 6;
    const int n    = nf / 6;
    const int o    = f * 16 + (lane & 15);
    const int c0   = n * 32 + (lane >> 4) * 8;
    bf16x8 v;
#pragma unroll
    for (int k = 0; k < 8; ++k)
        v[k] = f2b(pw[o * CIN + c0 + k] * (sc[c0 + k] + 1e-5f));
    *(bf16x8*)((char*)wf + (size_t)n * 8192 + (f * 64 + lane) * 16) = v;
}

// bias_o[o] = sum_c proj_w[o][c] * local_bias[c]   (96 blocks x 1 wave)
__global__ void prep_bias(const float* __restrict__ pw, const float* __restrict__ bi,
                          float* __restrict__ bias) {
    const int o = blockIdx.x;
    const int l = threadIdx.x;
    float s = 0.f;
    for (int c = l; c < CIN; c += 64) s += pw[o * CIN + c] * bi[c];
#pragma unroll
    for (int off = 32; off; off >>= 1) s += __shfl_down(s, off);
    if (l == 0) bias[o] = s;
}

// ---------------------------------------------------------------------------
// K1: y[b,o,px] = sum_c W[o][c]*x[b,c,px]   (bias in finalize; y bf16)
// Round-8 structure with W double-buffered (distance 1; covers L2 latency)
// and x triple-buffered (distance 2; covers HBM latency).
// LDS = 3*8KB (x) + 2*8KB (W) = 40 KB -> 4 blocks/CU, 32 waves/CU (VGPR<=64).
// vmcnt ledger (per wave, issues post-barrier, W before x):
//   prologue: x(0), W(0), x(1)            [3 outstanding]
//   STEP(n), n<=28: wait vmcnt(1) [queue x(n),W(n),x(n+1) -> retire x(n),W(n)],
//     barrier, frag reads, issue W(n+1) then x(n+2) (if <NCH), 3 MFMA.
//   STEP(29): vmcnt(0), no issues.
__global__ __launch_bounds__(512)
void conv_mfma(const float* __restrict__ x, const short* __restrict__ wf,
               short* __restrict__ yb) {
    const int tid  = threadIdx.x;
    const int lane = tid & 63;
    const int wv   = tid >> 6;          // 0..7
    const int m    = wv >> 2;           // o-half
    const int n    = wv & 3;            // px tile
    const int b    = blockIdx.y;
    const int px0  = blockIdx.x * 64;

    __shared__ __align__(16) char xsb[3 * 8192];   // x chunks [32ch][64px] f32
    __shared__ __align__(16) char wlb[2 * 8192];   // W chunks (6 frags + pad)

    const float* xbase = x + (size_t)b * CIN * PIX + px0;
    const char*  wfB   = (const char*)wf;

    // staging constants (one x-DMA + one W-DMA per wave per chunk)
    const int sch  = wv * 4 + (lane >> 4);               // channel within chunk
    const int sS   = (wv >> 1) & 3;                      // == (sch>>3)&3
    const int soff = (((lane >> 2) & 3) ^ sS) * 16 + (lane & 3) * 4;  // src px (floats)
    const int wsub = wv * 1024 + lane * 16;              // W copy offset (bytes)

    // compute constants
    const int kb    = lane >> 4;
    const int bcol  = (lane & 15) * 4;
    const int bslot = ((n ^ kb) & 3) * 64;
    const int babs  = kb * 2048 + bslot + bcol;          // + k*256, + XBI*8192
    const int abase = m * 3072 + lane * 16;              // + f*1024, + WBI*8192

    f32x4 acc0 = {0.f, 0.f, 0.f, 0.f};
    f32x4 acc1 = {0.f, 0.f, 0.f, 0.f};
    f32x4 acc2 = {0.f, 0.f, 0.f, 0.f};

#define XDMA(BS, c0)                                                             \
    GLOAD_LDS16(xbase + (size_t)((c0) + sch) * PIX + soff,                       \
                xsb + (BS) * 8192 + wv * 1024);
#define WDMA(N)                                                                  \
    GLOAD_LDS16(wfB + (size_t)(N) * 8192 + wsub,                                 \
                wlb + ((N) & 1) * 8192 + wv * 1024);

    // prologue: x(0), W(0), x(1)  (queue order matters for the ledger)
    XDMA(0, 0);
    WDMA(0);
    XDMA(1, 32);

    // STEP(n): wait vmcnt(VM) -> barrier -> frag reads -> issue W(n+1), x(n+2)
    //          -> 3 MFMA
#define STEP(n_, XBI, XBS, VM)                                                   \
    {                                                                            \
        asm volatile("s_waitcnt vmcnt(" #VM ")" ::: "memory");                   \
        asm volatile("s_barrier" ::: "memory");                                  \
        bf16x8 bfrag;                                                            \
        _Pragma("unroll")                                                        \
        for (int k = 0; k < 8; ++k)                                              \
            bfrag[k] = f2b(*(const float*)(xsb + (XBI) * 8192 + babs + k * 256));\
        const char* wp_ = wlb + ((n_) & 1) * 8192 + abase;                       \
        const bf16x8 af0 = *(const bf16x8*)(wp_);                                \
        const bf16x8 af1 = *(const bf16x8*)(wp_ + 1024);                         \
        const bf16x8 af2 = *(const bf16x8*)(wp_ + 2048);                         \
        if ((n_) + 1 < NCH) WDMA((n_) + 1);                                      \
        if ((n_) + 2 < NCH) XDMA(XBS, ((n_) + 2) * 32);                          \
        acc0 = __builtin_amdgcn_mfma_f32_16x16x32_bf16(af0, bfrag, acc0, 0,0,0); \
        acc1 = __builtin_amdgcn_mfma_f32_16x16x32_bf16(af1, bfrag, acc1, 0,0,0); \
        acc2 = __builtin_amdgcn_mfma_f32_16x16x32_bf16(af2, bfrag, acc2, 0,0,0); \
    }

#pragma unroll 1
    for (int mm = 0; mm < 9; ++mm) {
        const int n0 = mm * 3;
        STEP(n0 + 0, 0, 2, 1);
        STEP(n0 + 1, 1, 0, 1);
        STEP(n0 + 2, 2, 1, 1);
    }
    STEP(27, 0, 2, 1);
    STEP(28, 1, 0, 1);
    STEP(29, 2, 1, 0);   // drain
#undef STEP
#undef WDMA
#undef XDMA

    // epilogue: C/D col(px) = lane&15, row(o) = (lane>>4)*4 + r
    short* yp = yb + (size_t)b * COUT * PIX + px0 + n * 16 + (lane & 15);
    const int o0 = m * 48 + (lane >> 4) * 4;
#pragma unroll
    for (int r = 0; r < 4; ++r) yp[(size_t)(o0 +      r) * PIX] = f2b(acc0[r]);
#pragma unroll
    for (int r = 0; r < 4; ++r) yp[(size_t)(o0 + 16 + r) * PIX] = f2b(acc1[r]);
#pragma unroll
    for (int r = 0; r < 4; ++r) yp[(size_t)(o0 + 32 + r) * PIX] = f2b(acc2[r]);
}

// ---------------------------------------------------------------------------
// Antialiased 58->56 triangle weights; tap indices mapped to the 56-grid.
__device__ __forceinline__ void rweights56(int o, short* idx, float* wt) {
    const float ratio = 58.0f / 56.0f;
    const float kinv  = 56.0f / 58.0f;
    const float sf = ((float)o + 0.5f) * ratio - 0.5f;
    const int f0 = (int)floorf(sf);
    float sum = 0.f;
#pragma unroll
    for (int t = 0; t < 4; ++t) {
        int i = f0 - 1 + t;
        float w = fmaxf(1.0f - fabsf(sf - (float)i) * kinv, 0.0f);
        if (i < 0 || i > 57) w = 0.0f;
        idx[t] = (short)min(HH - 1, max(0, i - 1));
        wt[t] = w;
        sum += w;
    }
    const float inv = 1.0f / sum;
#pragma unroll
    for (int t = 0; t < 4; ++t) wt[t] *= inv;
}

// ---------------------------------------------------------------------------
// K2: EXACT round-8 finalize (1 px/thread; proven fastest).
__global__ __launch_bounds__(256)
void finalize(const float* __restrict__ x, const int* __restrict__ pad_hv,
              const int* __restrict__ idt, const short* __restrict__ yb,
              const float* __restrict__ bias, const float* __restrict__ alpha_p,
              float* __restrict__ out) {
    const int bc = blockIdx.x;          // b*96 + co
    const int co = bc % COUT;
    const int b  = bc / COUT;
    const int t  = threadIdx.x;

    __shared__ float  ylds[PIX];
    __shared__ float4 wt4[56];
    __shared__ short4 id4[56];
    __shared__ int   ish[10], isv[10], ipl[10];
    __shared__ float fid[10];

    if (t < 10) {
        const int g = t / 5;
        const int k = t - g * 5;
        const int slot = co * NK_ + k;
        ish[t] = pad_hv[slot * 4 + g];
        isv[t] = pad_hv[slot * 4 + 2 + g];
        fid[t] = (idt[slot * 2 + g] >= 0) ? 1.f : 0.f;
        ipl[t] = (g * (COUT * NK_) + slot) * PIX;
    }
    if (t < 56) {
        short ii[4]; float ww[4];
        rweights56(t, ii, ww);
        wt4[t] = make_float4(ww[0], ww[1], ww[2], ww[3]);
        id4[t] = make_short4(ii[0], ii[1], ii[2], ii[3]);
    }
    {
        const short* yp = yb + (size_t)bc * PIX;
#pragma unroll 1
        for (int i = t; i < PIX / 4; i += 256) {
            const short4 s4 = *(const short4*)(yp + i * 4);
            *(float4*)(ylds + i * 4) =
                make_float4(b2f(s4.x), b2f(s4.y), b2f(s4.z), b2f(s4.w));
        }
    }
    __syncthreads();

    int   ish_r[10], isv_r[10], ipl_r[10];
    float fid_r[10];
#pragma unroll
    for (int p = 0; p < 10; ++p) {
        ish_r[p] = ish[p]; isv_r[p] = isv[p];
        ipl_r[p] = ipl[p]; fid_r[p] = fid[p];
    }

    const float alpha = alpha_p[0];
    const float ia    = 1.0f - alpha;
    const float bco   = bias[co];
    const float* xb = x + (size_t)b * CIN * PIX;
    float* op = out + (size_t)bc * PIX;

#pragma unroll 1
    for (int px = t; px < PIX; px += 256) {
        const int h = (px * 18725) >> 20;
        const int w = px - h * WW_;
        const int hrow = px - w;

        float accg = 0.f;
#pragma unroll
        for (int p = 0; p < 10; ++p) {
            const float* xc = xb + ipl_r[p];
            const int jw = w + ish_r[p];
            const float mh = (jw >= -1 && jw <= WW_) ? 1.f : 0.f;
            accg += mh * xc[hrow + min(WW_ - 1, max(0, jw))];

            const int iv = h + isv_r[p];
            const float mv = (iv >= -1 && iv <= HH) ? 1.f : 0.f;
            accg += mv * xc[min(HH - 1, max(0, iv)) * WW_ + w];

            accg += fid_r[p] * xc[px];
        }

        const float4 ww4 = wt4[w];
        const short4 iw4 = id4[w];
        const float4 wh4 = wt4[h];
        const short4 ih4 = id4[h];
        float accl = 0.f;
#pragma unroll
        for (int a = 0; a < 4; ++a) {
            const int row = ((const short*)&ih4)[a] * WW_;
            const float* yr = ylds + row;
            float rs;
            rs = ww4.x * yr[iw4.x];
            rs = fmaf(ww4.y, yr[iw4.y], rs);
            rs = fmaf(ww4.z, yr[iw4.z], rs);
            rs = fmaf(ww4.w, yr[iw4.w], rs);
            accl = fmaf(((const float*)&wh4)[a], rs, accl);
        }
        accl += bco;

        op[px] = alpha * accg * (1.0f / 3.0f) + ia * accl;
    }
}

// ---------------------------------------------------------------------------
extern "C" void kernel_launch(void* const* d_in, const int* in_sizes, int n_in,
                              void* d_out, int out_size, void* d_ws, size_t ws_size,
                              hipStream_t stream) {
    const float* x      = (const float*)d_in[0];
    const int*   pad_hv = (const int*)d_in[1];
    const int*   idt    = (const int*)d_in[2];
    const float* lsc    = (const float*)d_in[3];
    const float* lbi    = (const float*)d_in[4];
    const float* pw     = (const float*)d_in[5];
    const float* alpha  = (const float*)d_in[6];
    float* out = (float*)d_out;

    float* ws   = (float*)d_ws;
    short* wf   = (short*)(ws + WF_OFF);
    float* bias = ws + BIAS_OFF;
    short* yb   = (short*)(ws + Y_OFF);

    prep_wb<<<(NCH * 6 * 64 + 255) / 256, 256, 0, stream>>>(pw, lsc, wf);
    prep_bias<<<COUT, 64, 0, stream>>>(pw, lbi, bias);
    conv_mfma<<<dim3(PIX / 64, B_), 512, 0, stream>>>(x, wf, yb);
    finalize<<<B_ * COUT, 256, 0, stream>>>(x, pad_hv, idt, yb, bias, alpha, out);
}